// Round 1
// baseline (432.073 us; speedup 1.0000x reference)
//
#include <hip/hip_runtime.h>
#include <stdint.h>

// Problem: Q[8192,512] f32, K[8192,512] f32 ->
//   scores_ij = -0.5*(sqrt(n2 + c*qd^2) + sqrt(n2 + c*kd^2)),  out = softmax
// Round-5 (on R4's 428 us; all kernels < 165 us so none hit top-k counters):
//   - gemm_exp: T3 minimal 2-phase pipeline. Double-buffered LDS (2x16KB),
//     prefetch tile t+1 via global_load_lds BEFORE computing tile t, then
//     raw `s_waitcnt vmcnt(0)` + s_barrier (ONE barrier/tile, prefetch
//     latency hides under the 16 MFMAs). __syncthreads() would re-drain the
//     just-issued prefetch -> raw barrier is required.
//   - rowsum_scale: 16B E loads (s16x8) instead of 8B (u16x4).
//   - XOR-swizzled LDS layout + epilogue transpose kept from R4 (verified).

#define NQ 8192
#define NK 8192
#define DIM 512
#define CSCALE 0.01f

typedef float f32x4 __attribute__((ext_vector_type(4)));
typedef short s16x8 __attribute__((ext_vector_type(8)));
typedef unsigned short u16x4 __attribute__((ext_vector_type(4)));

__device__ __forceinline__ unsigned short f2bf(float x) {
  union { float f; uint32_t u; } c; c.f = x;
  uint32_t u = c.u;
  return (unsigned short)((u + 0x7fffu + ((u >> 16) & 1u)) >> 16);
}

__device__ __forceinline__ float bf2f(unsigned short h) {
  union { uint32_t u; float f; } c; c.u = ((uint32_t)h) << 16;
  return c.f;
}

__device__ __forceinline__ s16x8 pack8(f32x4 a, f32x4 b) {
  s16x8 r;
  r[0]=(short)f2bf(a.x); r[1]=(short)f2bf(a.y);
  r[2]=(short)f2bf(a.z); r[3]=(short)f2bf(a.w);
  r[4]=(short)f2bf(b.x); r[5]=(short)f2bf(b.y);
  r[6]=(short)f2bf(b.z); r[7]=(short)f2bf(b.w);
  return r;
}

#define GLOAD_LDS16(g, l)                                                      \
  __builtin_amdgcn_global_load_lds(                                            \
      (const __attribute__((address_space(1))) void*)(g),                      \
      (__attribute__((address_space(3))) void*)(l), 16, 0, 0)

// ------------------------------------------------------------- prep (FAST)
__global__ __launch_bounds__(256) void prep_full_kernel(
    const float* __restrict__ q, const float* __restrict__ k,
    unsigned short* __restrict__ qbf, unsigned short* __restrict__ kbf,
    float* __restrict__ qq, float* __restrict__ kk) {
  int rowg = blockIdx.x * 4 + (threadIdx.x >> 6);  // 0..16383
  int lane = threadIdx.x & 63;
  const float* src; unsigned short* dst; float* nrm; int row;
  if (rowg < NQ) { src = q; dst = qbf; nrm = qq; row = rowg; }
  else           { src = k; dst = kbf; nrm = kk; row = rowg - NQ; }
  const float* p = src + (size_t)row * DIM + lane * 8;
  f32x4 a = *(const f32x4*)p;
  f32x4 b = *(const f32x4*)(p + 4);
  float ss = a.x*a.x + a.y*a.y + a.z*a.z + a.w*a.w
           + b.x*b.x + b.y*b.y + b.z*b.z + b.w*b.w;
  *(s16x8*)(dst + (size_t)row * DIM + lane * 8) = pack8(a, b);
#pragma unroll
  for (int mask = 1; mask < 64; mask <<= 1) ss += __shfl_xor(ss, mask, 64);
  if (lane == 0) nrm[row] = ss;
}

// ------------------------------------------------------------- prep (SAFE)
__global__ __launch_bounds__(256) void prep_norms_kernel(
    const float* __restrict__ q, const float* __restrict__ k,
    float* __restrict__ qq, float* __restrict__ kk) {
  int rowg = blockIdx.x * 4 + (threadIdx.x >> 6);
  int lane = threadIdx.x & 63;
  const float* src; float* nrm; int row;
  if (rowg < NQ) { src = q; nrm = qq; row = rowg; }
  else           { src = k; nrm = kk; row = rowg - NQ; }
  const float* p = src + (size_t)row * DIM + lane * 8;
  f32x4 a = *(const f32x4*)p;
  f32x4 b = *(const f32x4*)(p + 4);
  float ss = a.x*a.x + a.y*a.y + a.z*a.z + a.w*a.w
           + b.x*b.x + b.y*b.y + b.z*b.z + b.w*b.w;
#pragma unroll
  for (int mask = 1; mask < 64; mask <<= 1) ss += __shfl_xor(ss, mask, 64);
  if (lane == 0) nrm[row] = ss;
}

// ---- score from qk accumulator --------------------------------------------
__device__ __forceinline__ float score_fn(float qkv, float qqv, float kkv) {
  float n2 = fmaxf(qqv + kkv - 2.f * qkv, 0.f);
  float qd = qqv - qkv;
  float kd = qkv - kkv;
  return -0.5f * (__builtin_amdgcn_sqrtf(n2 + CSCALE * qd * qd) +
                  __builtin_amdgcn_sqrtf(n2 + CSCALE * kd * kd));
}

// ------------------------------------------------------------- GEMM (FAST)
// 128x128 tile, 256 threads = 4 waves (2x2 of 64x64), BK=32, 16x16x32 MFMA.
// LDS: double-buffered 2x16KB. Within a buffer: A = [0,8K), B = [8K,16K),
// both XOR-swizzled: 16B k-group g of row r lives at slot g ^ ((r>>1)&3).
// Pipeline: STAGE(t+1) -> ds_read+MFMA(t) -> vmcnt(0)+s_barrier. One barrier
// per K-step; prefetch latency hides under the MFMAs.
// Epilogue reuses smem[0:10K) as 4 wave-private 16x80 transpose pads.
__global__ __launch_bounds__(256) void gemm_exp_kernel(
    const unsigned short* __restrict__ qbf, const unsigned short* __restrict__ kbf,
    const float* __restrict__ qq, const float* __restrict__ kk,
    unsigned short* __restrict__ E) {
  __shared__ alignas(16) unsigned short smem[16384];  // 32 KB (2 x 16 KB)
  const int tid = threadIdx.x;
  const int m0 = blockIdx.y * 128;
  const int n0 = blockIdx.x * 128;
  const int wave = tid >> 6, lane = tid & 63;
  const int wr = wave >> 1, wc = wave & 1;
  const int quad = lane >> 4, lcol = lane & 15;

  // staging: thread t covers row srow (and srow+64), 16B slot (t&3); the
  // global k-group fetched is XOR-permuted so LDS slot g holds group
  // g ^ ((row>>1)&3). (row+64 keeps the same key: +64>>1 = +32, &3 = 0.)
  const int srow = tid >> 2;                       // 0..63
  const int gsw = (tid & 3) ^ ((srow >> 1) & 3);   // global 16B group to fetch
  const unsigned short* ga = qbf + (size_t)(m0 + srow) * DIM + gsw * 8;
  const unsigned short* gb = kbf + (size_t)(n0 + srow) * DIM + gsw * 8;
  char* labase = (char*)smem;
  const int stageoff = wave * 1024;                // wave-uniform LDS offset

  f32x4 acc[4][4];
#pragma unroll
  for (int mi = 0; mi < 4; ++mi)
#pragma unroll
    for (int ni = 0; ni < 4; ++ni) acc[mi][ni] = f32x4{0.f, 0.f, 0.f, 0.f};

  const int arow = wr * 64 + lcol;   // A frag: m = lane&15, k = quad*8+j
  const int brow = wc * 64 + lcol;
  const int swz = (lcol >> 1) & 3;   // = ((arow + mi*16)>>1)&3 for all mi
  const int qsw = quad ^ swz;        // swizzled slot of logical group `quad`

#define STAGE_TILE(bufbyte, ko)                                                \
  do {                                                                         \
    GLOAD_LDS16(ga + (ko), labase + (bufbyte) + stageoff);                     \
    GLOAD_LDS16(ga + (ko) + 64 * DIM, labase + (bufbyte) + stageoff + 4096);   \
    GLOAD_LDS16(gb + (ko), labase + (bufbyte) + 8192 + stageoff);              \
    GLOAD_LDS16(gb + (ko) + 64 * DIM,                                          \
                labase + (bufbyte) + 8192 + stageoff + 4096);                  \
  } while (0)

#define COMPUTE_TILE(bufbyte)                                                  \
  do {                                                                         \
    const s16x8* lA8 = (const s16x8*)(labase + (bufbyte));                     \
    const s16x8* lB8 = (const s16x8*)(labase + (bufbyte) + 8192);              \
    s16x8 af[4], bfr[4];                                                       \
    _Pragma("unroll")                                                          \
    for (int mi = 0; mi < 4; ++mi) af[mi] = lA8[(arow + mi * 16) * 4 + qsw];   \
    _Pragma("unroll")                                                          \
    for (int ni = 0; ni < 4; ++ni) bfr[ni] = lB8[(brow + ni * 16) * 4 + qsw];  \
    _Pragma("unroll")                                                          \
    for (int mi = 0; mi < 4; ++mi)                                             \
      _Pragma("unroll")                                                        \
      for (int ni = 0; ni < 4; ++ni)                                           \
        acc[mi][ni] = __builtin_amdgcn_mfma_f32_16x16x32_bf16(                 \
            af[mi], bfr[ni], acc[mi][ni], 0, 0, 0);                            \
  } while (0)

#define SYNC_PIPE()                                                            \
  do {                                                                         \
    asm volatile("s_waitcnt vmcnt(0)" ::: "memory");                           \
    __builtin_amdgcn_s_barrier();                                              \
  } while (0)

  const int NT = DIM / 32;  // 16 (even)
  STAGE_TILE(0, 0);
  SYNC_PIPE();
#pragma unroll 1
  for (int kt = 0; kt < NT; kt += 2) {
    // phase A: compute buf0 (tile kt), prefetch tile kt+1 -> buf1
    STAGE_TILE(16384, (kt + 1) * 32);
    COMPUTE_TILE(0);
    SYNC_PIPE();
    // phase B: compute buf1 (tile kt+1), prefetch tile kt+2 -> buf0
    if (kt + 2 < NT) STAGE_TILE(0, (kt + 2) * 32);
    COMPUTE_TILE(16384);
    SYNC_PIPE();
  }
#undef STAGE_TILE
#undef COMPUTE_TILE
#undef SYNC_PIPE

  // ---- epilogue: E = exp(score) -> bf16, LDS transpose, 128B-line stores --
  // C/D layout: col = lane&15, row = quad*4 + reg  [verified R2/R3 pass]
  unsigned short* tw = smem + wave * 1280;  // wave-private 16x80 shorts
  float kkv[4];
#pragma unroll
  for (int ni = 0; ni < 4; ++ni) kkv[ni] = kk[n0 + wc * 64 + ni * 16 + lcol];
#pragma unroll
  for (int mi = 0; mi < 4; ++mi) {
    const int ibase = m0 + wr * 64 + mi * 16 + quad * 4;  // rows ibase..+3
    float qqv[4];
#pragma unroll
    for (int r = 0; r < 4; ++r) qqv[r] = qq[ibase + r];
    // write: row16 = quad*4+r, stored col-group = ni ^ quad (bank spread)
#pragma unroll
    for (int ni = 0; ni < 4; ++ni)
#pragma unroll
      for (int r = 0; r < 4; ++r) {
        float e = __expf(score_fn(acc[mi][ni][r], qqv[r], kkv[ni]));
        tw[(quad * 4 + r) * 80 + ((ni ^ quad) * 16 + lcol)] = f2bf(e);
      }
    // read 16B/lane, 8 lanes cover one row's 64 cols = 128B line
#pragma unroll
    for (int j = 0; j < 2; ++j) {
      const int row16 = (lane >> 3) + j * 8;
      const int g = (lane & 7) >> 1;            // global col group 0..3
      const int off = row16 * 80 + ((g ^ (row16 >> 2)) * 16) + (lane & 1) * 8;
      s16x8 vv = *(const s16x8*)(tw + off);
      const int rowg = m0 + wr * 64 + mi * 16 + row16;
      *(s16x8*)(E + (size_t)rowg * NK + n0 + wc * 64 + (lane & 7) * 8) = vv;
    }
  }
}

// ------------------------------------------------- row sum + scale (FAST)
__global__ __launch_bounds__(256) void rowsum_scale_kernel(
    const unsigned short* __restrict__ E, float* __restrict__ out) {
  __shared__ float red[4];
  const int t = threadIdx.x;
  const int wave = t >> 6, lane = t & 63;
  const unsigned short* Erow = E + (size_t)blockIdx.x * NK;
  float* Orow = out + (size_t)blockIdx.x * NK;
  s16x8 ev[4];
  float s = 0.f;
#pragma unroll
  for (int j = 0; j < 4; ++j) {
    ev[j] = *(const s16x8*)(Erow + j * 2048 + t * 8);
    float a0 = bf2f((unsigned short)ev[j][0]) + bf2f((unsigned short)ev[j][1]);
    float a1 = bf2f((unsigned short)ev[j][2]) + bf2f((unsigned short)ev[j][3]);
    float a2 = bf2f((unsigned short)ev[j][4]) + bf2f((unsigned short)ev[j][5]);
    float a3 = bf2f((unsigned short)ev[j][6]) + bf2f((unsigned short)ev[j][7]);
    s += (a0 + a1) + (a2 + a3);
  }
#pragma unroll
  for (int mask = 1; mask < 64; mask <<= 1) s += __shfl_xor(s, mask, 64);
  if (lane == 0) red[wave] = s;
  __syncthreads();
  float z = 1.0f / ((red[0] + red[1]) + (red[2] + red[3]));
#pragma unroll
  for (int j = 0; j < 4; ++j) {
    f32x4 lo, hi;
    lo.x = bf2f((unsigned short)ev[j][0]) * z;
    lo.y = bf2f((unsigned short)ev[j][1]) * z;
    lo.z = bf2f((unsigned short)ev[j][2]) * z;
    lo.w = bf2f((unsigned short)ev[j][3]) * z;
    hi.x = bf2f((unsigned short)ev[j][4]) * z;
    hi.y = bf2f((unsigned short)ev[j][5]) * z;
    hi.z = bf2f((unsigned short)ev[j][6]) * z;
    hi.w = bf2f((unsigned short)ev[j][7]) * z;
    *(f32x4*)(Orow + j * 2048 + t * 8) = lo;
    *(f32x4*)(Orow + j * 2048 + t * 8 + 4) = hi;
  }
}

// ================== round-2 verified fallback kernels (MID / SAFE) ==========
__device__ __forceinline__ void score_epilogue(
    const f32x4 acc[4][4], const float* __restrict__ qq,
    const float* __restrict__ kk, float* __restrict__ S,
    int m0, int n0, int wr, int wc, int quad, int lcol) {
  float kkv[4];
#pragma unroll
  for (int ni = 0; ni < 4; ++ni) kkv[ni] = kk[n0 + wc * 64 + ni * 16 + lcol];
#pragma unroll
  for (int mi = 0; mi < 4; ++mi) {
    const int ibase = m0 + wr * 64 + mi * 16 + quad * 4;
    float qqv[4];
#pragma unroll
    for (int r = 0; r < 4; ++r) qqv[r] = qq[ibase + r];
#pragma unroll
    for (int ni = 0; ni < 4; ++ni) {
      const int col = n0 + wc * 64 + ni * 16 + lcol;
#pragma unroll
      for (int r = 0; r < 4; ++r)
        S[(size_t)(ibase + r) * NK + col] = score_fn(acc[mi][ni][r], qqv[r], kkv[ni]);
    }
  }
}

__global__ __launch_bounds__(256) void gemm_fast_kernel(
    const unsigned short* __restrict__ qbf, const unsigned short* __restrict__ kbf,
    const float* __restrict__ qq, const float* __restrict__ kk,
    float* __restrict__ S) {
  __shared__ unsigned short lA[128 * 32];
  __shared__ unsigned short lB[128 * 32];
  const int tid = threadIdx.x;
  const int m0 = blockIdx.y * 128;
  const int n0 = blockIdx.x * 128;
  const int wave = tid >> 6, lane = tid & 63;
  const int wr = wave >> 1, wc = wave & 1;
  const int quad = lane >> 4, lcol = lane & 15;
  const unsigned short* ga = qbf + (size_t)(m0 + (tid >> 2)) * DIM + (tid & 3) * 8;
  const unsigned short* gb = kbf + (size_t)(n0 + (tid >> 2)) * DIM + (tid & 3) * 8;
  char* la0 = (char*)lA + wave * 1024;
  char* lb0 = (char*)lB + wave * 1024;
  f32x4 acc[4][4];
#pragma unroll
  for (int mi = 0; mi < 4; ++mi)
#pragma unroll
    for (int ni = 0; ni < 4; ++ni) acc[mi][ni] = f32x4{0.f, 0.f, 0.f, 0.f};
  const s16x8* lA8 = (const s16x8*)lA;
  const s16x8* lB8 = (const s16x8*)lB;
  const int arow = wr * 64 + lcol;
  const int brow = wc * 64 + lcol;
  for (int kt = 0; kt < DIM / 32; ++kt) {
    const int ko = kt * 32;
    GLOAD_LDS16(ga + ko, la0);
    GLOAD_LDS16(ga + ko + 64 * DIM, la0 + 4096);
    GLOAD_LDS16(gb + ko, lb0);
    GLOAD_LDS16(gb + ko + 64 * DIM, lb0 + 4096);
    __syncthreads();
    s16x8 af[4], bfr[4];
#pragma unroll
    for (int mi = 0; mi < 4; ++mi) af[mi] = lA8[(arow + mi * 16) * 4 + quad];
#pragma unroll
    for (int ni = 0; ni < 4; ++ni) bfr[ni] = lB8[(brow + ni * 16) * 4 + quad];
#pragma unroll
    for (int mi = 0; mi < 4; ++mi)
#pragma unroll
      for (int ni = 0; ni < 4; ++ni)
        acc[mi][ni] = __builtin_amdgcn_mfma_f32_16x16x32_bf16(
            af[mi], bfr[ni], acc[mi][ni], 0, 0, 0);
    __syncthreads();
  }
  score_epilogue(acc, qq, kk, S, m0, n0, wr, wc, quad, lcol);
}

__global__ __launch_bounds__(256) void gemm_safe_kernel(
    const float* __restrict__ q, const float* __restrict__ k,
    const float* __restrict__ qq, const float* __restrict__ kk,
    float* __restrict__ S) {
  __shared__ unsigned short lA[128 * 32];
  __shared__ unsigned short lB[128 * 32];
  const int tid = threadIdx.x;
  const int m0 = blockIdx.y * 128;
  const int n0 = blockIdx.x * 128;
  const int wave = tid >> 6, lane = tid & 63;
  const int wr = wave >> 1, wc = wave & 1;
  const int quad = lane >> 4, lcol = lane & 15;
  const float* gaf = q + (size_t)(m0 + (tid >> 1)) * DIM + (tid & 1) * 16;
  const float* gbf = k + (size_t)(n0 + (tid >> 1)) * DIM + (tid & 1) * 16;
  unsigned short* wA = lA + (tid >> 1) * 32 + (tid & 1) * 16;
  unsigned short* wB = lB + (tid >> 1) * 32 + (tid & 1) * 16;
  f32x4 acc[4][4];
#pragma unroll
  for (int mi = 0; mi < 4; ++mi)
#pragma unroll
    for (int ni = 0; ni < 4; ++ni) acc[mi][ni] = f32x4{0.f, 0.f, 0.f, 0.f};
  const s16x8* lA8 = (const s16x8*)lA;
  const s16x8* lB8 = (const s16x8*)lB;
  const int arow = wr * 64 + lcol;
  const int brow = wc * 64 + lcol;
  for (int kt = 0; kt < DIM / 32; ++kt) {
    const float* pa = gaf + kt * 32;
    const float* pb = gbf + kt * 32;
    f32x4 a0 = *(const f32x4*)(pa), a1 = *(const f32x4*)(pa + 4);
    f32x4 a2 = *(const f32x4*)(pa + 8), a3 = *(const f32x4*)(pa + 12);
    f32x4 b0 = *(const f32x4*)(pb), b1 = *(const f32x4*)(pb + 4);
    f32x4 b2 = *(const f32x4*)(pb + 8), b3 = *(const f32x4*)(pb + 12);
    *(s16x8*)wA = pack8(a0, a1);
    *(s16x8*)(wA + 8) = pack8(a2, a3);
    *(s16x8*)wB = pack8(b0, b1);
    *(s16x8*)(wB + 8) = pack8(b2, b3);
    __syncthreads();
    s16x8 af[4], bfr[4];
#pragma unroll
    for (int mi = 0; mi < 4; ++mi) af[mi] = lA8[(arow + mi * 16) * 4 + quad];
#pragma unroll
    for (int ni = 0; ni < 4; ++ni) bfr[ni] = lB8[(brow + ni * 16) * 4 + quad];
#pragma unroll
    for (int mi = 0; mi < 4; ++mi)
#pragma unroll
      for (int ni = 0; ni < 4; ++ni)
        acc[mi][ni] = __builtin_amdgcn_mfma_f32_16x16x32_bf16(
            af[mi], bfr[ni], acc[mi][ni], 0, 0, 0);
    __syncthreads();
  }
  score_epilogue(acc, qq, kk, S, m0, n0, wr, wc, quad, lcol);
}

__global__ __launch_bounds__(256) void rowsoftmax_kernel(float* __restrict__ S) {
  __shared__ float red[8];
  const int t = threadIdx.x;
  const int wave = t >> 6, lane = t & 63;
  float* Srow = S + (size_t)blockIdx.x * NK;
  f32x4 v[8];
  float m = -1e30f;
#pragma unroll
  for (int j = 0; j < 8; ++j) {
    v[j] = *(const f32x4*)(Srow + j * 1024 + t * 4);
    m = fmaxf(m, fmaxf(fmaxf(v[j].x, v[j].y), fmaxf(v[j].z, v[j].w)));
  }
#pragma unroll
  for (int mask = 1; mask < 64; mask <<= 1) m = fmaxf(m, __shfl_xor(m, mask, 64));
  if (lane == 0) red[wave] = m;
  __syncthreads();
  m = fmaxf(fmaxf(red[0], red[1]), fmaxf(red[2], red[3]));
  float s = 0.f;
#pragma unroll
  for (int j = 0; j < 8; ++j) {
    v[j].x = __expf(v[j].x - m);
    v[j].y = __expf(v[j].y - m);
    v[j].z = __expf(v[j].z - m);
    v[j].w = __expf(v[j].w - m);
    s += (v[j].x + v[j].y) + (v[j].z + v[j].w);
  }
#pragma unroll
  for (int mask = 1; mask < 64; mask <<= 1) s += __shfl_xor(s, mask, 64);
  if (lane == 0) red[4 + wave] = s;
  __syncthreads();
  float z = 1.0f / ((red[4] + red[5]) + (red[6] + red[7]));
#pragma unroll
  for (int j = 0; j < 8; ++j) {
    v[j].x *= z; v[j].y *= z; v[j].z *= z; v[j].w *= z;
    *(f32x4*)(Srow + j * 1024 + t * 4) = v[j];
  }
}

// ---------------------------------------------------------------- launch
extern "C" void kernel_launch(void* const* d_in, const int* in_sizes, int n_in,
                              void* d_out, int out_size, void* d_ws, size_t ws_size,
                              hipStream_t stream) {
  const float* q = (const float*)d_in[0];
  const float* k = (const float*)d_in[1];
  float* S = (float*)d_out;
  char* ws = (char*)d_ws;

  // FAST: qbf(8M) + kbf(8M) + qq(32K) + kk(32K) + E(128M) = 151,126,016 B
  if (ws_size >= (size_t)151126016) {
    unsigned short* qbf = (unsigned short*)(ws);
    unsigned short* kbf = (unsigned short*)(ws + 8388608);
    float* qq = (float*)(ws + 16777216);
    float* kk = (float*)(ws + 16777216 + 32768);
    unsigned short* E = (unsigned short*)(ws + 16908288);
    prep_full_kernel<<<4096, 256, 0, stream>>>(q, k, qbf, kbf, qq, kk);
    gemm_exp_kernel<<<dim3(64, 64), 256, 0, stream>>>(qbf, kbf, qq, kk, E);
    rowsum_scale_kernel<<<NQ, 256, 0, stream>>>(E, S);
  } else if (ws_size >= (size_t)16842752) {  // MID: round-2 verified path
    unsigned short* qbf = (unsigned short*)(ws);
    unsigned short* kbf = (unsigned short*)(ws + 8388608);
    float* qq = (float*)(ws + 16777216);
    float* kk = (float*)(ws + 16777216 + 32768);
    prep_full_kernel<<<4096, 256, 0, stream>>>(q, k, qbf, kbf, qq, kk);
    gemm_fast_kernel<<<dim3(64, 64), 256, 0, stream>>>(qbf, kbf, qq, kk, S);
    rowsoftmax_kernel<<<NQ, 256, 0, stream>>>(S);
  } else {  // SAFE: norms only in ws
    float* qq = (float*)(ws);
    float* kk = (float*)(ws + 32768);
    prep_norms_kernel<<<4096, 256, 0, stream>>>(q, k, qq, kk);
    gemm_safe_kernel<<<dim3(64, 64), 256, 0, stream>>>(q, k, qq, kk, S);
    rowsoftmax_kernel<<<NQ, 256, 0, stream>>>(S);
  }
}

// Round 3
// 418.904 us; speedup vs baseline: 1.0314x; 1.0314x over previous
//
#include <hip/hip_runtime.h>
#include <stdint.h>

// Problem: Q[8192,512] f32, K[8192,512] f32 ->
//   scores_ij = -0.5*(sqrt(n2 + c*qd^2) + sqrt(n2 + c*kd^2)),  out = softmax
// Round-7: R6 (256^2, depth-4, 128KB LDS) died with "container failed
// twice" (no counters). Audit found no logic bug; de-risking the resource
// surface while keeping the structure change:
//   - 256x256 tile, BK=32, 512 thr = 8 waves (2Mx4N), per-wave 128x64
//   - DEPTH-3 LDS ring (3x32KB = 96KB, was 128KB): stage tile kt+2 while
//     computing kt; overwritten buffer was read in iteration kt-1 and
//     drained before that iteration's barrier (no WAR race)
//   - counted vmcnt(4) once per K-step (8 loads in flight, never 0 in the
//     steady loop); tail drains at kt=14
//   - 2 MFMA clusters of 16 per K-step wrapped in s_setprio(1) (T5)
//   - swizzle: linear LDS dest + inverse-permuted global src + permuted
//     ds_read, key(row) = (row ^ row>>2) & 3  (rule #21 both-sides)
//   - T1 XCD-bijective block swizzle (1024 blocks % 8 == 0 -> simple form)
// Fragment layout + exp/transpose epilogue carried VERBATIM from the
// R4-verified kernel (same per-acc MFMA order -> bitwise-identical acc).

#define NQ 8192
#define NK 8192
#define DIM 512
#define CSCALE 0.01f

typedef float f32x4 __attribute__((ext_vector_type(4)));
typedef short s16x8 __attribute__((ext_vector_type(8)));
typedef unsigned short u16x4 __attribute__((ext_vector_type(4)));

__device__ __forceinline__ unsigned short f2bf(float x) {
  union { float f; uint32_t u; } c; c.f = x;
  uint32_t u = c.u;
  return (unsigned short)((u + 0x7fffu + ((u >> 16) & 1u)) >> 16);
}

__device__ __forceinline__ float bf2f(unsigned short h) {
  union { uint32_t u; float f; } c; c.u = ((uint32_t)h) << 16;
  return c.f;
}

__device__ __forceinline__ s16x8 pack8(f32x4 a, f32x4 b) {
  s16x8 r;
  r[0]=(short)f2bf(a.x); r[1]=(short)f2bf(a.y);
  r[2]=(short)f2bf(a.z); r[3]=(short)f2bf(a.w);
  r[4]=(short)f2bf(b.x); r[5]=(short)f2bf(b.y);
  r[6]=(short)f2bf(b.z); r[7]=(short)f2bf(b.w);
  return r;
}

#define GLOAD_LDS16(g, l)                                                      \
  __builtin_amdgcn_global_load_lds(                                            \
      (const __attribute__((address_space(1))) void*)(g),                      \
      (__attribute__((address_space(3))) void*)(l), 16, 0, 0)

// ------------------------------------------------------------- prep (FAST)
__global__ __launch_bounds__(256) void prep_full_kernel(
    const float* __restrict__ q, const float* __restrict__ k,
    unsigned short* __restrict__ qbf, unsigned short* __restrict__ kbf,
    float* __restrict__ qq, float* __restrict__ kk) {
  int rowg = blockIdx.x * 4 + (threadIdx.x >> 6);  // 0..16383
  int lane = threadIdx.x & 63;
  const float* src; unsigned short* dst; float* nrm; int row;
  if (rowg < NQ) { src = q; dst = qbf; nrm = qq; row = rowg; }
  else           { src = k; dst = kbf; nrm = kk; row = rowg - NQ; }
  const float* p = src + (size_t)row * DIM + lane * 8;
  f32x4 a = *(const f32x4*)p;
  f32x4 b = *(const f32x4*)(p + 4);
  float ss = a.x*a.x + a.y*a.y + a.z*a.z + a.w*a.w
           + b.x*b.x + b.y*b.y + b.z*b.z + b.w*b.w;
  *(s16x8*)(dst + (size_t)row * DIM + lane * 8) = pack8(a, b);
#pragma unroll
  for (int mask = 1; mask < 64; mask <<= 1) ss += __shfl_xor(ss, mask, 64);
  if (lane == 0) nrm[row] = ss;
}

// ------------------------------------------------------------- prep (SAFE)
__global__ __launch_bounds__(256) void prep_norms_kernel(
    const float* __restrict__ q, const float* __restrict__ k,
    float* __restrict__ qq, float* __restrict__ kk) {
  int rowg = blockIdx.x * 4 + (threadIdx.x >> 6);
  int lane = threadIdx.x & 63;
  const float* src; float* nrm; int row;
  if (rowg < NQ) { src = q; nrm = qq; row = rowg; }
  else           { src = k; nrm = kk; row = rowg - NQ; }
  const float* p = src + (size_t)row * DIM + lane * 8;
  f32x4 a = *(const f32x4*)p;
  f32x4 b = *(const f32x4*)(p + 4);
  float ss = a.x*a.x + a.y*a.y + a.z*a.z + a.w*a.w
           + b.x*b.x + b.y*b.y + b.z*b.z + b.w*b.w;
#pragma unroll
  for (int mask = 1; mask < 64; mask <<= 1) ss += __shfl_xor(ss, mask, 64);
  if (lane == 0) nrm[row] = ss;
}

// ---- score from qk accumulator --------------------------------------------
__device__ __forceinline__ float score_fn(float qkv, float qqv, float kkv) {
  float n2 = fmaxf(qqv + kkv - 2.f * qkv, 0.f);
  float qd = qqv - qkv;
  float kd = qkv - kkv;
  return -0.5f * (__builtin_amdgcn_sqrtf(n2 + CSCALE * qd * qd) +
                  __builtin_amdgcn_sqrtf(n2 + CSCALE * kd * kd));
}

// ------------------------------------------------------------- GEMM (FAST)
// 256x256 tile, 512 threads = 8 waves (2M x 4N), per-wave 128x64 output,
// BK=32, 16x16x32 MFMA. LDS: 3-buffer ring x 32KB (A 16KB + B 16KB each).
// Staging: per inst, 512 thr x 16B = 8KB = 128 rows x 64B. Thread t covers
// row srow=t>>2 (and srow+128), 16B slot t&3; fetched global group is
// (t&3) ^ key(row), key(r) = (r ^ (r>>2)) & 3; LDS linear so ds_read at
// slot quad ^ key recovers logical group quad with spread banks.
__global__ __launch_bounds__(512, 2) void gemm_exp256_kernel(
    const unsigned short* __restrict__ qbf, const unsigned short* __restrict__ kbf,
    const float* __restrict__ qq, const float* __restrict__ kk,
    unsigned short* __restrict__ E) {
  __shared__ alignas(16) unsigned short smem[49152];  // 96 KB (3 x 32 KB)
  const int tid = threadIdx.x;
  // T1: bijective XCD swizzle (1024 blocks, 1024 % 8 == 0 -> simple form).
  // Dispatch-linear id lin -> XCD lin%8 owns contiguous chunk of 128 tiles.
  const int lin = blockIdx.y * 32 + blockIdx.x;
  const int tile = (lin & 7) * 128 + (lin >> 3);
  const int m0 = (tile >> 5) * 256;
  const int n0 = (tile & 31) * 256;
  const int wave = tid >> 6, lane = tid & 63;
  const int wrM = wave >> 2, wcN = wave & 3;           // 2 x 4 wave grid
  const int quad = lane >> 4, lcol = lane & 15;

  // staging addresses (per-lane global, wave-uniform LDS base)
  const int srow = tid >> 2;                           // 0..127
  const int kkey = (srow ^ (srow >> 2)) & 3;           // same for srow+128
  const int gsw = (tid & 3) ^ kkey;                    // global group to fetch
  const unsigned short* gaA = qbf + (size_t)(m0 + srow) * DIM + gsw * 8;
  const unsigned short* gbB = kbf + (size_t)(n0 + srow) * DIM + gsw * 8;
  char* sm8 = (char*)smem;
  const int wso = wave * 1024;                         // wave slice in 8KB inst

  // buf b: A at b*32768 (rows 0-127 [0,8K), rows 128-255 [8K,16K)),
  //        B at b*32768+16384, same split
#define STAGE_A(b, kt)                                                         \
  do {                                                                         \
    GLOAD_LDS16(gaA + (kt) * 32, sm8 + (b) * 32768 + wso);                     \
    GLOAD_LDS16(gaA + (kt) * 32 + 128 * DIM, sm8 + (b) * 32768 + 8192 + wso);  \
  } while (0)
#define STAGE_B(b, kt)                                                         \
  do {                                                                         \
    GLOAD_LDS16(gbB + (kt) * 32, sm8 + (b) * 32768 + 16384 + wso);             \
    GLOAD_LDS16(gbB + (kt) * 32 + 128 * DIM,                                   \
                sm8 + (b) * 32768 + 16384 + 8192 + wso);                       \
  } while (0)

  f32x4 acc[8][4];
#pragma unroll
  for (int mi = 0; mi < 8; ++mi)
#pragma unroll
    for (int ni = 0; ni < 4; ++ni) acc[mi][ni] = f32x4{0.f, 0.f, 0.f, 0.f};

  // read-side: logical 16B group of a row is quad; stored slot = quad ^ key,
  // key = (row ^ row>>2)&3 = (lcol ^ lcol>>2)&3 (16-multiples vanish mod 4).
  const s16x8* L8 = (const s16x8*)smem;
  const int slot = quad ^ ((lcol ^ (lcol >> 2)) & 3);
  const int arow = wrM * 128 + lcol;   // + mi*16 (mi 0..7)
  const int brow = wcN * 64 + lcol;    // + ni*16 (ni 0..3)
  // s16x8 units: buf*2048 | A: row*4 + slot | B: +1024 + row*4 + slot

  STAGE_A(0, 0); STAGE_B(0, 0);
  STAGE_A(1, 1); STAGE_B(1, 1);
  asm volatile("s_waitcnt vmcnt(4)" ::: "memory");  // tile 0 landed
  __builtin_amdgcn_s_barrier();

  int cur = 0, stg = 2;  // compute buf for kt; stage buf = (kt+2)%3
#pragma unroll 1
  for (int kt = 0; kt < 16; ++kt) {
    const int bb = cur * 2048;
    s16x8 bfr[4], af[4];
    // ---- phase 0: B frags + A rows 0-63 of wave, stage A(kt+2), 16 MFMA
#pragma unroll
    for (int ni = 0; ni < 4; ++ni)
      bfr[ni] = L8[bb + 1024 + (brow + ni * 16) * 4 + slot];
#pragma unroll
    for (int mi = 0; mi < 4; ++mi)
      af[mi] = L8[bb + (arow + mi * 16) * 4 + slot];
    if (kt <= 13) STAGE_A(stg, kt + 2);
    __builtin_amdgcn_s_setprio(1);
#pragma unroll
    for (int mi = 0; mi < 4; ++mi)
#pragma unroll
      for (int ni = 0; ni < 4; ++ni)
        acc[mi][ni] = __builtin_amdgcn_mfma_f32_16x16x32_bf16(
            af[mi], bfr[ni], acc[mi][ni], 0, 0, 0);
    __builtin_amdgcn_s_setprio(0);
    // ---- phase 1: A rows 64-127 of wave, stage B(kt+2), 16 MFMA
#pragma unroll
    for (int mi = 0; mi < 4; ++mi)
      af[mi] = L8[bb + (arow + 64 + mi * 16) * 4 + slot];
    if (kt <= 13) STAGE_B(stg, kt + 2);
    __builtin_amdgcn_s_setprio(1);
#pragma unroll
    for (int mi = 0; mi < 4; ++mi)
#pragma unroll
      for (int ni = 0; ni < 4; ++ni)
        acc[4 + mi][ni] = __builtin_amdgcn_mfma_f32_16x16x32_bf16(
            af[mi], bfr[ni], acc[4 + mi][ni], 0, 0, 0);
    __builtin_amdgcn_s_setprio(0);
    // ---- counted drain: tile kt+1 landed; never 0 until the tail
    if (kt <= 13)      asm volatile("s_waitcnt vmcnt(4)" ::: "memory");
    else               asm volatile("s_waitcnt vmcnt(0)" ::: "memory");
    __builtin_amdgcn_s_barrier();
    cur = (cur == 2) ? 0 : cur + 1;
    stg = (stg == 2) ? 0 : stg + 1;
  }
#undef STAGE_A
#undef STAGE_B

  // ---- epilogue: E = exp(score) -> bf16, LDS transpose, 128B-line stores --
  // C/D layout: col = lane&15, row = quad*4 + reg  [verified R2/R3/R4]
  // (all waves past final barrier; smem reusable. tw: 8 waves x 2560B = 20KB)
  unsigned short* tw = smem + wave * 1280;  // wave-private 16x80 shorts
  float kkv[4];
#pragma unroll
  for (int ni = 0; ni < 4; ++ni) kkv[ni] = kk[n0 + wcN * 64 + ni * 16 + lcol];
#pragma unroll
  for (int mi = 0; mi < 8; ++mi) {
    const int ibase = m0 + wrM * 128 + mi * 16 + quad * 4;  // rows ibase..+3
    float qqv[4];
#pragma unroll
    for (int r = 0; r < 4; ++r) qqv[r] = qq[ibase + r];
    // write: row16 = quad*4+r, stored col-group = ni ^ quad (bank spread)
#pragma unroll
    for (int ni = 0; ni < 4; ++ni)
#pragma unroll
      for (int r = 0; r < 4; ++r) {
        float e = __expf(score_fn(acc[mi][ni][r], qqv[r], kkv[ni]));
        tw[(quad * 4 + r) * 80 + ((ni ^ quad) * 16 + lcol)] = f2bf(e);
      }
    // read 16B/lane, 8 lanes cover one row's 64 cols = 128B line
#pragma unroll
    for (int j = 0; j < 2; ++j) {
      const int row16 = (lane >> 3) + j * 8;
      const int g = (lane & 7) >> 1;            // global col group 0..3
      const int off = row16 * 80 + ((g ^ (row16 >> 2)) * 16) + (lane & 1) * 8;
      s16x8 vv = *(const s16x8*)(tw + off);
      const int rowg = m0 + wrM * 128 + mi * 16 + row16;
      *(s16x8*)(E + (size_t)rowg * NK + n0 + wcN * 64 + (lane & 7) * 8) = vv;
    }
  }
}

// ------------------------------------------------- row sum + scale (FAST)
__global__ __launch_bounds__(256) void rowsum_scale_kernel(
    const unsigned short* __restrict__ E, float* __restrict__ out) {
  __shared__ float red[4];
  const int t = threadIdx.x;
  const int wave = t >> 6, lane = t & 63;
  const unsigned short* Erow = E + (size_t)blockIdx.x * NK;
  float* Orow = out + (size_t)blockIdx.x * NK;
  s16x8 ev[4];
  float s = 0.f;
#pragma unroll
  for (int j = 0; j < 4; ++j) {
    ev[j] = *(const s16x8*)(Erow + j * 2048 + t * 8);
    float a0 = bf2f((unsigned short)ev[j][0]) + bf2f((unsigned short)ev[j][1]);
    float a1 = bf2f((unsigned short)ev[j][2]) + bf2f((unsigned short)ev[j][3]);
    float a2 = bf2f((unsigned short)ev[j][4]) + bf2f((unsigned short)ev[j][5]);
    float a3 = bf2f((unsigned short)ev[j][6]) + bf2f((unsigned short)ev[j][7]);
    s += (a0 + a1) + (a2 + a3);
  }
#pragma unroll
  for (int mask = 1; mask < 64; mask <<= 1) s += __shfl_xor(s, mask, 64);
  if (lane == 0) red[wave] = s;
  __syncthreads();
  float z = 1.0f / ((red[0] + red[1]) + (red[2] + red[3]));
#pragma unroll
  for (int j = 0; j < 4; ++j) {
    f32x4 lo, hi;
    lo.x = bf2f((unsigned short)ev[j][0]) * z;
    lo.y = bf2f((unsigned short)ev[j][1]) * z;
    lo.z = bf2f((unsigned short)ev[j][2]) * z;
    lo.w = bf2f((unsigned short)ev[j][3]) * z;
    hi.x = bf2f((unsigned short)ev[j][4]) * z;
    hi.y = bf2f((unsigned short)ev[j][5]) * z;
    hi.z = bf2f((unsigned short)ev[j][6]) * z;
    hi.w = bf2f((unsigned short)ev[j][7]) * z;
    *(f32x4*)(Orow + j * 2048 + t * 8) = lo;
    *(f32x4*)(Orow + j * 2048 + t * 8 + 4) = hi;
  }
}

// ================== round-2 verified fallback kernels (MID / SAFE) ==========
__device__ __forceinline__ void score_epilogue(
    const f32x4 acc[4][4], const float* __restrict__ qq,
    const float* __restrict__ kk, float* __restrict__ S,
    int m0, int n0, int wr, int wc, int quad, int lcol) {
  float kkv[4];
#pragma unroll
  for (int ni = 0; ni < 4; ++ni) kkv[ni] = kk[n0 + wc * 64 + ni * 16 + lcol];
#pragma unroll
  for (int mi = 0; mi < 4; ++mi) {
    const int ibase = m0 + wr * 64 + mi * 16 + quad * 4;
    float qqv[4];
#pragma unroll
    for (int r = 0; r < 4; ++r) qqv[r] = qq[ibase + r];
#pragma unroll
    for (int ni = 0; ni < 4; ++ni) {
      const int col = n0 + wc * 64 + ni * 16 + lcol;
#pragma unroll
      for (int r = 0; r < 4; ++r)
        S[(size_t)(ibase + r) * NK + col] = score_fn(acc[mi][ni][r], qqv[r], kkv[ni]);
    }
  }
}

__global__ __launch_bounds__(256) void gemm_fast_kernel(
    const unsigned short* __restrict__ qbf, const unsigned short* __restrict__ kbf,
    const float* __restrict__ qq, const float* __restrict__ kk,
    float* __restrict__ S) {
  __shared__ unsigned short lA[128 * 32];
  __shared__ unsigned short lB[128 * 32];
  const int tid = threadIdx.x;
  const int m0 = blockIdx.y * 128;
  const int n0 = blockIdx.x * 128;
  const int wave = tid >> 6, lane = tid & 63;
  const int wr = wave >> 1, wc = wave & 1;
  const int quad = lane >> 4, lcol = lane & 15;
  const unsigned short* ga = qbf + (size_t)(m0 + (tid >> 2)) * DIM + (tid & 3) * 8;
  const unsigned short* gb = kbf + (size_t)(n0 + (tid >> 2)) * DIM + (tid & 3) * 8;
  char* la0 = (char*)lA + wave * 1024;
  char* lb0 = (char*)lB + wave * 1024;
  f32x4 acc[4][4];
#pragma unroll
  for (int mi = 0; mi < 4; ++mi)
#pragma unroll
    for (int ni = 0; ni < 4; ++ni) acc[mi][ni] = f32x4{0.f, 0.f, 0.f, 0.f};
  const s16x8* lA8 = (const s16x8*)lA;
  const s16x8* lB8 = (const s16x8*)lB;
  const int arow = wr * 64 + lcol;
  const int brow = wc * 64 + lcol;
  for (int kt = 0; kt < DIM / 32; ++kt) {
    const int ko = kt * 32;
    GLOAD_LDS16(ga + ko, la0);
    GLOAD_LDS16(ga + ko + 64 * DIM, la0 + 4096);
    GLOAD_LDS16(gb + ko, lb0);
    GLOAD_LDS16(gb + ko + 64 * DIM, lb0 + 4096);
    __syncthreads();
    s16x8 af[4], bfr[4];
#pragma unroll
    for (int mi = 0; mi < 4; ++mi) af[mi] = lA8[(arow + mi * 16) * 4 + quad];
#pragma unroll
    for (int ni = 0; ni < 4; ++ni) bfr[ni] = lB8[(brow + ni * 16) * 4 + quad];
#pragma unroll
    for (int mi = 0; mi < 4; ++mi)
#pragma unroll
      for (int ni = 0; ni < 4; ++ni)
        acc[mi][ni] = __builtin_amdgcn_mfma_f32_16x16x32_bf16(
            af[mi], bfr[ni], acc[mi][ni], 0, 0, 0);
    __syncthreads();
  }
  score_epilogue(acc, qq, kk, S, m0, n0, wr, wc, quad, lcol);
}

__global__ __launch_bounds__(256) void gemm_safe_kernel(
    const float* __restrict__ q, const float* __restrict__ k,
    const float* __restrict__ qq, const float* __restrict__ kk,
    float* __restrict__ S) {
  __shared__ unsigned short lA[128 * 32];
  __shared__ unsigned short lB[128 * 32];
  const int tid = threadIdx.x;
  const int m0 = blockIdx.y * 128;
  const int n0 = blockIdx.x * 128;
  const int wave = tid >> 6, lane = tid & 63;
  const int wr = wave >> 1, wc = wave & 1;
  const int quad = lane >> 4, lcol = lane & 15;
  const float* gaf = q + (size_t)(m0 + (tid >> 1)) * DIM + (tid & 1) * 16;
  const float* gbf = k + (size_t)(n0 + (tid >> 1)) * DIM + (tid & 1) * 16;
  unsigned short* wA = lA + (tid >> 1) * 32 + (tid & 1) * 16;
  unsigned short* wB = lB + (tid >> 1) * 32 + (tid & 1) * 16;
  f32x4 acc[4][4];
#pragma unroll
  for (int mi = 0; mi < 4; ++mi)
#pragma unroll
    for (int ni = 0; ni < 4; ++ni) acc[mi][ni] = f32x4{0.f, 0.f, 0.f, 0.f};
  const s16x8* lA8 = (const s16x8*)lA;
  const s16x8* lB8 = (const s16x8*)lB;
  const int arow = wr * 64 + lcol;
  const int brow = wc * 64 + lcol;
  for (int kt = 0; kt < DIM / 32; ++kt) {
    const float* pa = gaf + kt * 32;
    const float* pb = gbf + kt * 32;
    f32x4 a0 = *(const f32x4*)(pa), a1 = *(const f32x4*)(pa + 4);
    f32x4 a2 = *(const f32x4*)(pa + 8), a3 = *(const f32x4*)(pa + 12);
    f32x4 b0 = *(const f32x4*)(pb), b1 = *(const f32x4*)(pb + 4);
    f32x4 b2 = *(const f32x4*)(pb + 8), b3 = *(const f32x4*)(pb + 12);
    *(s16x8*)wA = pack8(a0, a1);
    *(s16x8*)(wA + 8) = pack8(a2, a3);
    *(s16x8*)wB = pack8(b0, b1);
    *(s16x8*)(wB + 8) = pack8(b2, b3);
    __syncthreads();
    s16x8 af[4], bfr[4];
#pragma unroll
    for (int mi = 0; mi < 4; ++mi) af[mi] = lA8[(arow + mi * 16) * 4 + quad];
#pragma unroll
    for (int ni = 0; ni < 4; ++ni) bfr[ni] = lB8[(brow + ni * 16) * 4 + quad];
#pragma unroll
    for (int mi = 0; mi < 4; ++mi)
#pragma unroll
      for (int ni = 0; ni < 4; ++ni)
        acc[mi][ni] = __builtin_amdgcn_mfma_f32_16x16x32_bf16(
            af[mi], bfr[ni], acc[mi][ni], 0, 0, 0);
    __syncthreads();
  }
  score_epilogue(acc, qq, kk, S, m0, n0, wr, wc, quad, lcol);
}

__global__ __launch_bounds__(256) void rowsoftmax_kernel(float* __restrict__ S) {
  __shared__ float red[8];
  const int t = threadIdx.x;
  const int wave = t >> 6, lane = t & 63;
  float* Srow = S + (size_t)blockIdx.x * NK;
  f32x4 v[8];
  float m = -1e30f;
#pragma unroll
  for (int j = 0; j < 8; ++j) {
    v[j] = *(const f32x4*)(Srow + j * 1024 + t * 4);
    m = fmaxf(m, fmaxf(fmaxf(v[j].x, v[j].y), fmaxf(v[j].z, v[j].w)));
  }
#pragma unroll
  for (int mask = 1; mask < 64; mask <<= 1) m = fmaxf(m, __shfl_xor(m, mask, 64));
  if (lane == 0) red[wave] = m;
  __syncthreads();
  m = fmaxf(fmaxf(red[0], red[1]), fmaxf(red[2], red[3]));
  float s = 0.f;
#pragma unroll
  for (int j = 0; j < 8; ++j) {
    v[j].x = __expf(v[j].x - m);
    v[j].y = __expf(v[j].y - m);
    v[j].z = __expf(v[j].z - m);
    v[j].w = __expf(v[j].w - m);
    s += (v[j].x + v[j].y) + (v[j].z + v[j].w);
  }
#pragma unroll
  for (int mask = 1; mask < 64; mask <<= 1) s += __shfl_xor(s, mask, 64);
  if (lane == 0) red[4 + wave] = s;
  __syncthreads();
  float z = 1.0f / ((red[4] + red[5]) + (red[6] + red[7]));
#pragma unroll
  for (int j = 0; j < 8; ++j) {
    v[j].x *= z; v[j].y *= z; v[j].z *= z; v[j].w *= z;
    *(f32x4*)(Srow + j * 1024 + t * 4) = v[j];
  }
}

// ---------------------------------------------------------------- launch
extern "C" void kernel_launch(void* const* d_in, const int* in_sizes, int n_in,
                              void* d_out, int out_size, void* d_ws, size_t ws_size,
                              hipStream_t stream) {
  const float* q = (const float*)d_in[0];
  const float* k = (const float*)d_in[1];
  float* S = (float*)d_out;
  char* ws = (char*)d_ws;

  // FAST: qbf(8M) + kbf(8M) + qq(32K) + kk(32K) + E(128M) = 151,126,016 B
  if (ws_size >= (size_t)151126016) {
    unsigned short* qbf = (unsigned short*)(ws);
    unsigned short* kbf = (unsigned short*)(ws + 8388608);
    float* qq = (float*)(ws + 16777216);
    float* kk = (float*)(ws + 16777216 + 32768);
    unsigned short* E = (unsigned short*)(ws + 16908288);
    prep_full_kernel<<<4096, 256, 0, stream>>>(q, k, qbf, kbf, qq, kk);
    gemm_exp256_kernel<<<dim3(32, 32), 512, 0, stream>>>(qbf, kbf, qq, kk, E);
    rowsum_scale_kernel<<<NQ, 256, 0, stream>>>(E, S);
  } else if (ws_size >= (size_t)16842752) {  // MID: round-2 verified path
    unsigned short* qbf = (unsigned short*)(ws);
    unsigned short* kbf = (unsigned short*)(ws + 8388608);
    float* qq = (float*)(ws + 16777216);
    float* kk = (float*)(ws + 16777216 + 32768);
    prep_full_kernel<<<4096, 256, 0, stream>>>(q, k, qbf, kbf, qq, kk);
    gemm_fast_kernel<<<dim3(64, 64), 256, 0, stream>>>(qbf, kbf, qq, kk, S);
    rowsoftmax_kernel<<<NQ, 256, 0, stream>>>(S);
  } else {  // SAFE: norms only in ws
    float* qq = (float*)(ws);
    float* kk = (float*)(ws + 32768);
    prep_norms_kernel<<<4096, 256, 0, stream>>>(q, k, qq, kk);
    gemm_safe_kernel<<<dim3(64, 64), 256, 0, stream>>>(q, k, qq, kk, S);
    rowsoftmax_kernel<<<NQ, 256, 0, stream>>>(S);
  }
}